// Round 1
// baseline (1160.414 us; speedup 1.0000x reference)
//
#include <hip/hip_runtime.h>
#include <cstdint>
#include <cstddef>

// MapFormerWM: 2-layer transformer with SO(2)-block "generalized RoPE".
// Key simplification: prefix product of commuting 2x2 rotations == rotation by
// cumsum of angles -> plain RoPE with theta = cumsum_t(a_emb @ lie_w + lie_b).
//
// DTYPE ASSUMPTION (round 1): float inputs are fp32, output fp32, per harness
// contract. Internal compute: bf16 MFMA with fp32 accumulate.

using u16 = unsigned short;
using u32 = unsigned int;

typedef __bf16 bf16x8 __attribute__((ext_vector_type(8)));
typedef float  f32x4  __attribute__((ext_vector_type(4)));

__device__ __forceinline__ u16 f2bf(float f) {
  union { float f; u32 u; } v; v.f = f;
  u32 r = v.u + 0x7fffu + ((v.u >> 16) & 1u);   // RNE
  return (u16)(r >> 16);
}
__device__ __forceinline__ float bf2f(u16 u) {
  union { u32 u; float f; } v; v.u = ((u32)u) << 16;
  return v.f;
}

// async global->LDS, 16B per lane; LDS dest must be wave-uniform base + lane*16
__device__ __forceinline__ void gll16(const void* g, void* l) {
  __builtin_amdgcn_global_load_lds((__attribute__((address_space(1))) void*)(g),
                                   (__attribute__((address_space(3))) void*)(l),
                                   16, 0, 0);
}

// ---------------------------------------------------------------- transpose
// in: fp32 (K,N) row-major  ->  out: bf16 (N,K) row-major
__global__ __launch_bounds__(256) void transpose_f2b(
    const float* __restrict__ in, u16* __restrict__ out, int K, int N)
{
  __shared__ float tile[32][33];
  const int n0 = blockIdx.x * 32, k0 = blockIdx.y * 32;
  const int tx = threadIdx.x, ty = threadIdx.y;   // (32,8)
  #pragma unroll
  for (int i = 0; i < 4; ++i) {
    int kk = ty + i * 8;
    tile[kk][tx] = in[(size_t)(k0 + kk) * N + n0 + tx];
  }
  __syncthreads();
  #pragma unroll
  for (int i = 0; i < 4; ++i) {
    int nn = ty + i * 8;
    out[(size_t)(n0 + nn) * K + k0 + tx] = f2bf(tile[tx][nn]);
  }
}

// ---------------------------------------------------------------- delta
// delta[b,t,r] = dot(action_emb[actions[b,t]], lie_w[:,r]) + lie_b[r]
__global__ __launch_bounds__(256) void delta_kernel(
    const int* __restrict__ actions, const float* __restrict__ aemb,
    const float* __restrict__ lie_w, const float* __restrict__ lie_b,
    float* __restrict__ delta)
{
  const int bt = blockIdx.x;                 // 0..2047
  const int a = actions[bt];
  const float* e = aemb + (size_t)a * 1024;
  const int r = threadIdx.x >> 3, part = threadIdx.x & 7;
  float s = 0.f;
  const int j0 = part * 128;
  for (int j = j0; j < j0 + 128; ++j)
    s += e[j] * lie_w[(size_t)j * 32 + r];
  s += __shfl_xor(s, 1); s += __shfl_xor(s, 2); s += __shfl_xor(s, 4);
  if (part == 0) delta[(size_t)bt * 32 + r] = s + lie_b[r];
}

// ---------------------------------------------------------------- scan
// theta = inclusive cumsum_t(delta); store (cos,sin). block = one (b,r)
__global__ __launch_bounds__(256) void scan_theta(
    const float* __restrict__ delta, float2* __restrict__ cs)
{
  const int b = blockIdx.x >> 5, r = blockIdx.x & 31;
  const int tid = threadIdx.x;
  float d0[4];
  #pragma unroll
  for (int i = 0; i < 4; ++i)
    d0[i] = delta[((size_t)b * 1024 + tid * 4 + i) * 32 + r];
  d0[1] += d0[0]; d0[2] += d0[1]; d0[3] += d0[2];
  __shared__ float sc[256];
  sc[tid] = d0[3];
  __syncthreads();
  for (int off = 1; off < 256; off <<= 1) {
    float v = (tid >= off) ? sc[tid - off] : 0.f;
    __syncthreads();
    sc[tid] += v;
    __syncthreads();
  }
  float ex = sc[tid] - d0[3];
  #pragma unroll
  for (int i = 0; i < 4; ++i) {
    float th = ex + d0[i];
    float2 v; v.x = cosf(th); v.y = sinf(th);
    cs[((size_t)b * 1024 + tid * 4 + i) * 32 + r] = v;
  }
}

// ---------------------------------------------------------------- gather x
__global__ __launch_bounds__(256) void gather_x(
    const int* __restrict__ obs, const float* __restrict__ emb,
    float* __restrict__ x)
{
  const int idx = blockIdx.x * 256 + threadIdx.x;   // 2048*256
  const int bt = idx >> 8, c = idx & 255;
  *(float4*)(x + (size_t)bt * 1024 + c * 4) =
      *(const float4*)(emb + (size_t)obs[bt] * 1024 + c * 4);
}

// ---------------------------------------------------------------- layernorm
// x fp32 (rows of 1024) -> bf16 out, per-row mean/var (ddof=0), eps 1e-5
__global__ __launch_bounds__(256) void ln_bf16(
    const float* __restrict__ x, const float* __restrict__ g,
    const float* __restrict__ bb, u16* __restrict__ out)
{
  const int row = blockIdx.x, tid = threadIdx.x;
  const float4 v = *(const float4*)(x + (size_t)row * 1024 + tid * 4);
  float s = v.x + v.y + v.z + v.w;
  float q = v.x * v.x + v.y * v.y + v.z * v.z + v.w * v.w;
  #pragma unroll
  for (int off = 32; off; off >>= 1) { s += __shfl_xor(s, off); q += __shfl_xor(q, off); }
  __shared__ float red[8];
  const int wid = tid >> 6, lane = tid & 63;
  if (lane == 0) { red[wid] = s; red[4 + wid] = q; }
  __syncthreads();
  s = red[0] + red[1] + red[2] + red[3];
  q = red[4] + red[5] + red[6] + red[7];
  const float mean = s * (1.f / 1024.f);
  const float var = q * (1.f / 1024.f) - mean * mean;
  const float rstd = rsqrtf(var + 1e-5f);
  float xx[4] = {v.x, v.y, v.z, v.w};
  u32 lo, hi;
  {
    float a0 = (xx[0] - mean) * rstd * g[tid * 4 + 0] + bb[tid * 4 + 0];
    float a1 = (xx[1] - mean) * rstd * g[tid * 4 + 1] + bb[tid * 4 + 1];
    float a2 = (xx[2] - mean) * rstd * g[tid * 4 + 2] + bb[tid * 4 + 2];
    float a3 = (xx[3] - mean) * rstd * g[tid * 4 + 3] + bb[tid * 4 + 3];
    lo = (u32)f2bf(a0) | ((u32)f2bf(a1) << 16);
    hi = (u32)f2bf(a2) | ((u32)f2bf(a3) << 16);
  }
  uint2 pk; pk.x = lo; pk.y = hi;
  *(uint2*)(out + (size_t)row * 1024 + tid * 4) = pk;
}

// ---------------------------------------------------------------- rotate Q,K
// in-place pairwise rotation by theta[b,t,r] (same for every head)
__global__ __launch_bounds__(256) void rotate_qk(
    u16* Q, u16* Kp, const float2* __restrict__ cs)
{
  const int idx = blockIdx.x * 256 + threadIdx.x;   // 2*1024*16*32 / 2 per tensor
  const int r = idx & 31, h = (idx >> 5) & 15, bt = idx >> 9;
  const float2 c = cs[(size_t)bt * 32 + r];
  const size_t addr = ((size_t)bt * 16 + h) * 64 + 2 * r;
  {
    u32 u = *(u32*)(Q + addr);
    float q0 = bf2f((u16)(u & 0xffff)), q1 = bf2f((u16)(u >> 16));
    float r0 = c.x * q0 - c.y * q1, r1 = c.y * q0 + c.x * q1;
    *(u32*)(Q + addr) = (u32)f2bf(r0) | ((u32)f2bf(r1) << 16);
  }
  {
    u32 u = *(u32*)(Kp + addr);
    float q0 = bf2f((u16)(u & 0xffff)), q1 = bf2f((u16)(u >> 16));
    float r0 = c.x * q0 - c.y * q1, r1 = c.y * q0 + c.x * q1;
    *(u32*)(Kp + addr) = (u32)f2bf(r0) | ((u32)f2bf(r1) << 16);
  }
}

// ---------------------------------------------------------------- GEMM (m97-style)
// C(M,N) = A(M,K)bf16 @ Bt(N,K)bf16^T  + epilogue
// MODE 0: +bias -> bf16       MODE 1: +bias+residual -> fp32 (in-place x)
// MODE 2: +bias, gelu -> bf16 MODE 3: +bias -> fp32
// MODE 4: +bias -> bf16 scattered V^T store [b,h,d,t] (N=1024, T=1024, H=16)
template<int MODE>
__global__ __launch_bounds__(256) void gemm_bt(
    const u16* __restrict__ A, const u16* __restrict__ Bt,
    const float* __restrict__ bias, const float* res,
    void* outp, int M, int N, int K)
{
  __shared__ u16 As[128 * 32];
  __shared__ u16 Bs[128 * 32];
  const int tid = threadIdx.x;
  const int lane = tid & 63, wid = tid >> 6;
  const int wm = wid & 1, wn = wid >> 1;
  const int quad = lane >> 4, lq = lane & 15;
  const int m0 = blockIdx.x * 128, n0 = blockIdx.y * 128;

  f32x4 acc[4][4] = {};
  const int nkb = K >> 5;
  for (int kb = 0; kb < nkb; ++kb) {
    __syncthreads();
    const int kof = kb * 32;
    #pragma unroll
    for (int rep = 0; rep < 2; ++rep) {
      int c = rep * 256 + tid;
      int row = c >> 2, kc = (c & 3) * 8;
      gll16(A + (size_t)(m0 + row) * K + kof + kc, As + c * 8);
      gll16(Bt + (size_t)(n0 + row) * K + kof + kc, Bs + c * 8);
    }
    __syncthreads();
    bf16x8 a[4], b[4];
    #pragma unroll
    for (int i = 0; i < 4; ++i)
      a[i] = *(const bf16x8*)(As + (wm * 64 + i * 16 + lq) * 32 + quad * 8);
    #pragma unroll
    for (int j = 0; j < 4; ++j)
      b[j] = *(const bf16x8*)(Bs + (wn * 64 + j * 16 + lq) * 32 + quad * 8);
    #pragma unroll
    for (int i = 0; i < 4; ++i)
      #pragma unroll
      for (int j = 0; j < 4; ++j)
        acc[i][j] = __builtin_amdgcn_mfma_f32_16x16x32_bf16(a[i], b[j], acc[i][j], 0, 0, 0);
  }

  #pragma unroll
  for (int i = 0; i < 4; ++i) {
    const int gm0 = m0 + wm * 64 + i * 16 + quad * 4;
    #pragma unroll
    for (int j = 0; j < 4; ++j) {
      const int gn = n0 + wn * 64 + j * 16 + lq;
      const float bv = bias[gn];
      f32x4 v = acc[i][j];
      if constexpr (MODE == 0) {
        u16* O = (u16*)outp;
        #pragma unroll
        for (int r = 0; r < 4; ++r) O[(size_t)(gm0 + r) * N + gn] = f2bf(v[r] + bv);
      } else if constexpr (MODE == 1) {
        float* O = (float*)outp;
        #pragma unroll
        for (int r = 0; r < 4; ++r) {
          size_t idx = (size_t)(gm0 + r) * N + gn;
          O[idx] = res[idx] + v[r] + bv;
        }
      } else if constexpr (MODE == 2) {
        u16* O = (u16*)outp;
        #pragma unroll
        for (int r = 0; r < 4; ++r) {
          float t = v[r] + bv;
          O[(size_t)(gm0 + r) * N + gn] =
              f2bf(0.5f * t * (1.f + erff(t * 0.70710678118654752f)));
        }
      } else if constexpr (MODE == 3) {
        float* O = (float*)outp;
        #pragma unroll
        for (int r = 0; r < 4; ++r) O[(size_t)(gm0 + r) * N + gn] = v[r] + bv;
      } else {  // MODE 4: V^T
        u16* O = (u16*)outp;
        const int b = gm0 >> 10, t = gm0 & 1023;
        u32 lo = (u32)f2bf(v[0] + bv) | ((u32)f2bf(v[1] + bv) << 16);
        u32 hi = (u32)f2bf(v[2] + bv) | ((u32)f2bf(v[3] + bv) << 16);
        uint2 pk; pk.x = lo; pk.y = hi;
        size_t idx = ((size_t)(b * 16 + (gn >> 6)) * 64 + (gn & 63)) * 1024 + t;
        *(uint2*)(O + idx) = pk;
      }
    }
  }
}

// ---------------------------------------------------------------- attention
// flash-style causal attention, 64x64 tiles, one block per (qt, b*H+h)
// Q,K: [B,T,H,64] bf16 (rotated); Vt: [B,H,64,T] bf16; O: [B,T,H,64] bf16
__global__ __launch_bounds__(256) void attn_kernel(
    const u16* __restrict__ Q, const u16* __restrict__ K,
    const u16* __restrict__ Vt, u16* __restrict__ O)
{
  __shared__ u16 Qs[64 * 80];   // [qrow][d],  stride 80 (160B, 16B-aligned)
  __shared__ u16 Ks[64 * 80];   // [krow][d]
  __shared__ u16 Vs[64 * 80];   // [d][krow]
  __shared__ u16 Ps[64 * 80];   // [qrow][krow]

  const int tid = threadIdx.x;
  const int lane = tid & 63, wq = tid >> 6;
  const int quad = lane >> 4, lq = lane & 15;
  const int qt = blockIdx.x;         // 0..15
  const int bh = blockIdx.y;         // 0..31
  const int b = bh >> 4, h = bh & 15;

  const size_t qbase = (size_t)b * 1024 * 1024 + (size_t)qt * 64 * 1024 + h * 64;
  #pragma unroll
  for (int rep = 0; rep < 3; ++rep) {
    int c = rep * 256 + tid;
    if (c < 640) {
      int row = c / 10, rr = c % 10; if (rr >= 8) rr = 0;  // pad slots get dup data
      gll16(Q + qbase + (size_t)row * 1024 + rr * 8, Qs + c * 8);
    }
  }

  f32x4 o_acc[4] = {};
  float m_run[4], l_run[4];
  #pragma unroll
  for (int r = 0; r < 4; ++r) { m_run[r] = -1e30f; l_run[r] = 0.f; }

  for (int kt = 0; kt <= qt; ++kt) {
    __syncthreads();   // previous-iter LDS reads complete
    const size_t kbase = (size_t)b * 1024 * 1024 + (size_t)kt * 64 * 1024 + h * 64;
    const size_t vbase = (size_t)bh * 64 * 1024 + kt * 64;
    #pragma unroll
    for (int rep = 0; rep < 3; ++rep) {
      int c = rep * 256 + tid;
      if (c < 640) {
        int row = c / 10, rr = c % 10; if (rr >= 8) rr = 0;
        gll16(K + kbase + (size_t)row * 1024 + rr * 8, Ks + c * 8);
        gll16(Vt + vbase + (size_t)row * 1024 + rr * 8, Vs + c * 8);
      }
    }
    __syncthreads();   // staging (incl. Qs on first iter) visible

    // S = Q K^T  (wave owns q-rows [wq*16, wq*16+16))
    f32x4 s[4] = {};
    #pragma unroll
    for (int ks = 0; ks < 2; ++ks) {
      bf16x8 aq = *(const bf16x8*)(Qs + (wq * 16 + lq) * 80 + ks * 32 + quad * 8);
      #pragma unroll
      for (int j = 0; j < 4; ++j) {
        bf16x8 bk = *(const bf16x8*)(Ks + (j * 16 + lq) * 80 + ks * 32 + quad * 8);
        s[j] = __builtin_amdgcn_mfma_f32_16x16x32_bf16(aq, bk, s[j], 0, 0, 0);
      }
    }

    // scale + causal mask + row max
    float mt[4] = {-1e30f, -1e30f, -1e30f, -1e30f};
    const int qr0 = qt * 64 + wq * 16 + quad * 4;
    const bool diag = (kt == qt);
    #pragma unroll
    for (int j = 0; j < 4; ++j) {
      const int kp = kt * 64 + j * 16 + lq;
      #pragma unroll
      for (int r = 0; r < 4; ++r) {
        float v = s[j][r] * 0.125f;
        if (diag && kp > qr0 + r) v = -1e30f;
        s[j][r] = v;
        mt[r] = fmaxf(mt[r], v);
      }
    }
    #pragma unroll
    for (int r = 0; r < 4; ++r)
      #pragma unroll
      for (int off = 1; off < 16; off <<= 1)
        mt[r] = fmaxf(mt[r], __shfl_xor(mt[r], off));

    float alpha[4], rs[4];
    #pragma unroll
    for (int r = 0; r < 4; ++r) {
      float mn = fmaxf(m_run[r], mt[r]);
      alpha[r] = __expf(m_run[r] - mn);
      m_run[r] = mn;
      rs[r] = 0.f;
    }
    #pragma unroll
    for (int j = 0; j < 4; ++j)
      #pragma unroll
      for (int r = 0; r < 4; ++r) {
        float p = __expf(s[j][r] - m_run[r]);
        s[j][r] = p;
        rs[r] += p;
      }
    #pragma unroll
    for (int r = 0; r < 4; ++r) {
      #pragma unroll
      for (int off = 1; off < 16; off <<= 1)
        rs[r] += __shfl_xor(rs[r], off);
      l_run[r] = l_run[r] * alpha[r] + rs[r];
      o_acc[0][r] *= alpha[r]; o_acc[1][r] *= alpha[r];
      o_acc[2][r] *= alpha[r]; o_acc[3][r] *= alpha[r];
    }

    // P -> LDS (D-layout -> A-layout round trip); rows are wave-private
    #pragma unroll
    for (int j = 0; j < 4; ++j)
      #pragma unroll
      for (int r = 0; r < 4; ++r)
        Ps[(wq * 16 + quad * 4 + r) * 80 + j * 16 + lq] = f2bf(s[j][r]);
    asm volatile("s_waitcnt lgkmcnt(0)" ::: "memory");

    // O += P V
    #pragma unroll
    for (int ks = 0; ks < 2; ++ks) {
      bf16x8 ap = *(const bf16x8*)(Ps + (wq * 16 + lq) * 80 + ks * 32 + quad * 8);
      #pragma unroll
      for (int jd = 0; jd < 4; ++jd) {
        bf16x8 bv = *(const bf16x8*)(Vs + (jd * 16 + lq) * 80 + ks * 32 + quad * 8);
        o_acc[jd] = __builtin_amdgcn_mfma_f32_16x16x32_bf16(ap, bv, o_acc[jd], 0, 0, 0);
      }
    }
  }

  #pragma unroll
  for (int r = 0; r < 4; ++r) {
    const int t = qt * 64 + wq * 16 + quad * 4 + r;
    const float inv = 1.f / l_run[r];
    const size_t base = ((size_t)(b * 1024 + t) * 16 + h) * 64;
    #pragma unroll
    for (int jd = 0; jd < 4; ++jd)
      O[base + jd * 16 + lq] = f2bf(o_acc[jd][r] * inv);
  }
}

// ---------------------------------------------------------------- launch
extern "C" void kernel_launch(void* const* d_in, const int* in_sizes, int n_in,
                              void* d_out, int out_size, void* d_ws, size_t ws_size,
                              hipStream_t stream) {
  const int*   actions      = (const int*)d_in[0];
  const int*   observations = (const int*)d_in[1];
  const float* action_emb   = (const float*)d_in[2];
  const float* obs_emb      = (const float*)d_in[3];
  const float* lie_w        = (const float*)d_in[4];
  const float* lie_b        = (const float*)d_in[5];
  const float* Wq = (const float*)d_in[6];  const float* bq = (const float*)d_in[7];
  const float* Wk = (const float*)d_in[8];  const float* bk = (const float*)d_in[9];
  const float* Wv = (const float*)d_in[10]; const float* bvp = (const float*)d_in[11];
  const float* Wo = (const float*)d_in[12]; const float* bo = (const float*)d_in[13];
  const float* ln1_g = (const float*)d_in[14]; const float* ln1_b = (const float*)d_in[15];
  const float* ln2_g = (const float*)d_in[16]; const float* ln2_b = (const float*)d_in[17];
  const float* w1 = (const float*)d_in[18]; const float* b1 = (const float*)d_in[19];
  const float* w2 = (const float*)d_in[20]; const float* b2 = (const float*)d_in[21];
  const float* out_g = (const float*)d_in[22]; const float* out_bln = (const float*)d_in[23];
  const float* out_w = (const float*)d_in[24]; const float* out_b = (const float*)d_in[25];
  float* out = (float*)d_out;

  char* basep = (char*)d_ws;
  size_t off = 0;
  auto take = [&](size_t bytes) -> char* {
    char* p = basep + off;
    off += (bytes + 255) & ~(size_t)255;
    return p;
  };
  u16* wqT = (u16*)take((size_t)2 * 1024 * 1024 * 2);
  u16* wkT = (u16*)take((size_t)2 * 1024 * 1024 * 2);
  u16* wvT = (u16*)take((size_t)2 * 1024 * 1024 * 2);
  u16* woT = (u16*)take((size_t)2 * 1024 * 1024 * 2);
  u16* w1T = (u16*)take((size_t)2 * 4096 * 1024 * 2);
  u16* w2T = (u16*)take((size_t)2 * 4096 * 1024 * 2);
  u16* owT = (u16*)take((size_t)16384 * 1024 * 2);
  float*  xbuf  = (float*)take((size_t)2048 * 1024 * 4);
  u16*    hbuf  = (u16*)take((size_t)2048 * 1024 * 2);
  u16*    qbuf  = (u16*)take((size_t)2048 * 1024 * 2);
  u16*    kbuf  = (u16*)take((size_t)2048 * 1024 * 2);
  u16*    vtg   = (u16*)take((size_t)2048 * 1024 * 2);
  u16*    obuf  = (u16*)take((size_t)2048 * 1024 * 2);
  u16*    ubuf  = (u16*)take((size_t)2048 * 4096 * 2);
  float*  dbuf  = (float*)take((size_t)2048 * 32 * 4);
  float2* csbuf = (float2*)take((size_t)2048 * 32 * 8);

  const dim3 tb(32, 8);
  for (int l = 0; l < 2; ++l) {
    size_t mo = (size_t)l * 1024 * 1024;
    transpose_f2b<<<dim3(32, 32), tb, 0, stream>>>(Wq + mo, wqT + mo, 1024, 1024);
    transpose_f2b<<<dim3(32, 32), tb, 0, stream>>>(Wk + mo, wkT + mo, 1024, 1024);
    transpose_f2b<<<dim3(32, 32), tb, 0, stream>>>(Wv + mo, wvT + mo, 1024, 1024);
    transpose_f2b<<<dim3(32, 32), tb, 0, stream>>>(Wo + mo, woT + mo, 1024, 1024);
    size_t fo = (size_t)l * 4096 * 1024;
    transpose_f2b<<<dim3(128, 32), tb, 0, stream>>>(w1 + fo, w1T + fo, 1024, 4096);
    transpose_f2b<<<dim3(32, 128), tb, 0, stream>>>(w2 + fo, w2T + fo, 4096, 1024);
  }
  transpose_f2b<<<dim3(512, 32), tb, 0, stream>>>(out_w, owT, 1024, 16384);

  delta_kernel<<<2048, 256, 0, stream>>>(actions, action_emb, lie_w, lie_b, dbuf);
  scan_theta<<<64, 256, 0, stream>>>(dbuf, csbuf);
  gather_x<<<2048, 256, 0, stream>>>(observations, obs_emb, xbuf);

  for (int l = 0; l < 2; ++l) {
    size_t mo = (size_t)l * 1024 * 1024, fo = (size_t)l * 4096 * 1024;
    ln_bf16<<<2048, 256, 0, stream>>>(xbuf, ln1_g + l * 1024, ln1_b + l * 1024, hbuf);
    gemm_bt<0><<<dim3(16, 8), 256, 0, stream>>>(hbuf, wqT + mo, bq + l * 1024, nullptr, qbuf, 2048, 1024, 1024);
    gemm_bt<0><<<dim3(16, 8), 256, 0, stream>>>(hbuf, wkT + mo, bk + l * 1024, nullptr, kbuf, 2048, 1024, 1024);
    gemm_bt<4><<<dim3(16, 8), 256, 0, stream>>>(hbuf, wvT + mo, bvp + l * 1024, nullptr, vtg, 2048, 1024, 1024);
    rotate_qk<<<4096, 256, 0, stream>>>(qbuf, kbuf, csbuf);
    attn_kernel<<<dim3(16, 32), 256, 0, stream>>>(qbuf, kbuf, vtg, obuf);
    gemm_bt<1><<<dim3(16, 8), 256, 0, stream>>>(obuf, woT + mo, bo + l * 1024, xbuf, xbuf, 2048, 1024, 1024);
    ln_bf16<<<2048, 256, 0, stream>>>(xbuf, ln2_g + l * 1024, ln2_b + l * 1024, hbuf);
    gemm_bt<2><<<dim3(16, 32), 256, 0, stream>>>(hbuf, w1T + fo, b1 + l * 4096, nullptr, ubuf, 2048, 4096, 1024);
    gemm_bt<1><<<dim3(16, 8), 256, 0, stream>>>(ubuf, w2T + fo, b2 + l * 1024, xbuf, xbuf, 2048, 1024, 4096);
  }
  ln_bf16<<<2048, 256, 0, stream>>>(xbuf, out_g, out_bln, hbuf);
  gemm_bt<3><<<dim3(16, 128), 256, 0, stream>>>(hbuf, owT, out_b, nullptr, out, 2048, 16384, 1024);
}

// Round 2
// 1107.733 us; speedup vs baseline: 1.0476x; 1.0476x over previous
//
#include <hip/hip_runtime.h>
#include <cstdint>
#include <cstddef>

// MapFormerWM: 2-layer transformer with SO(2)-block "generalized RoPE".
// Prefix product of commuting 2x2 rotations == rotation by cumsum of angles.
// Round 2: XCD-aware GEMM swizzle, fused QKV GEMM (+rotation epilogue),
// vectorized weight transposes.

using u16 = unsigned short;
using u32 = unsigned int;

typedef __bf16 bf16x8 __attribute__((ext_vector_type(8)));
typedef float  f32x4  __attribute__((ext_vector_type(4)));

__device__ __forceinline__ u16 f2bf(float f) {
  union { float f; u32 u; } v; v.f = f;
  u32 r = v.u + 0x7fffu + ((v.u >> 16) & 1u);   // RNE
  return (u16)(r >> 16);
}
__device__ __forceinline__ float bf2f(u16 u) {
  union { u32 u; float f; } v; v.u = ((u32)u) << 16;
  return v.f;
}

// async global->LDS, 16B per lane; LDS dest must be wave-uniform base + lane*16
__device__ __forceinline__ void gll16(const void* g, void* l) {
  __builtin_amdgcn_global_load_lds((__attribute__((address_space(1))) void*)(g),
                                   (__attribute__((address_space(3))) void*)(l),
                                   16, 0, 0);
}

// ---------------------------------------------------------------- transpose
// in: fp32 (K,N) row-major -> out: bf16 (N,K) row-major. 64x64 tiles.
__global__ __launch_bounds__(256) void transpose_f2b(
    const float* __restrict__ in, u16* __restrict__ out, int K, int N)
{
  __shared__ float tile[64][65];
  const int n0 = blockIdx.x * 64, k0 = blockIdx.y * 64;
  const int tid = threadIdx.x;
  const int rr = tid >> 4, cc = (tid & 15) * 4;
  #pragma unroll
  for (int p = 0; p < 4; ++p) {
    int kk = rr + p * 16;
    float4 v = *(const float4*)(in + (size_t)(k0 + kk) * N + n0 + cc);
    tile[kk][cc] = v.x; tile[kk][cc + 1] = v.y;
    tile[kk][cc + 2] = v.z; tile[kk][cc + 3] = v.w;
  }
  __syncthreads();
  #pragma unroll
  for (int p = 0; p < 4; ++p) {
    int nn = rr + p * 16;
    u32 lo = (u32)f2bf(tile[cc + 0][nn]) | ((u32)f2bf(tile[cc + 1][nn]) << 16);
    u32 hi = (u32)f2bf(tile[cc + 2][nn]) | ((u32)f2bf(tile[cc + 3][nn]) << 16);
    uint2 pk; pk.x = lo; pk.y = hi;
    *(uint2*)(out + (size_t)(n0 + nn) * K + k0 + cc) = pk;
  }
}

// fused qkv bias: out[l*3072 + r] from bq/bk/bv (each [L][1024])
__global__ __launch_bounds__(256) void fuse_bias(
    const float* __restrict__ bq, const float* __restrict__ bk,
    const float* __restrict__ bv, float* __restrict__ out)
{
  int idx = blockIdx.x * 256 + threadIdx.x;   // 6144
  int l = idx / 3072, r = idx % 3072;
  const float* src = (r < 1024) ? bq : ((r < 2048) ? bk : bv);
  out[idx] = src[l * 1024 + (r & 1023)];
}

// ---------------------------------------------------------------- delta
__global__ __launch_bounds__(256) void delta_kernel(
    const int* __restrict__ actions, const float* __restrict__ aemb,
    const float* __restrict__ lie_w, const float* __restrict__ lie_b,
    float* __restrict__ delta)
{
  const int bt = blockIdx.x;                 // 0..2047
  const int a = actions[bt];
  const float* e = aemb + (size_t)a * 1024;
  const int r = threadIdx.x >> 3, part = threadIdx.x & 7;
  float s = 0.f;
  const int j0 = part * 128;
  for (int j = j0; j < j0 + 128; ++j)
    s += e[j] * lie_w[(size_t)j * 32 + r];
  s += __shfl_xor(s, 1); s += __shfl_xor(s, 2); s += __shfl_xor(s, 4);
  if (part == 0) delta[(size_t)bt * 32 + r] = s + lie_b[r];
}

// ---------------------------------------------------------------- scan
__global__ __launch_bounds__(256) void scan_theta(
    const float* __restrict__ delta, float2* __restrict__ cs)
{
  const int b = blockIdx.x >> 5, r = blockIdx.x & 31;
  const int tid = threadIdx.x;
  float d0[4];
  #pragma unroll
  for (int i = 0; i < 4; ++i)
    d0[i] = delta[((size_t)b * 1024 + tid * 4 + i) * 32 + r];
  d0[1] += d0[0]; d0[2] += d0[1]; d0[3] += d0[2];
  __shared__ float sc[256];
  sc[tid] = d0[3];
  __syncthreads();
  for (int off = 1; off < 256; off <<= 1) {
    float v = (tid >= off) ? sc[tid - off] : 0.f;
    __syncthreads();
    sc[tid] += v;
    __syncthreads();
  }
  float ex = sc[tid] - d0[3];
  #pragma unroll
  for (int i = 0; i < 4; ++i) {
    float th = ex + d0[i];
    float2 v; v.x = cosf(th); v.y = sinf(th);
    cs[((size_t)b * 1024 + tid * 4 + i) * 32 + r] = v;
  }
}

// ---------------------------------------------------------------- gather x
__global__ __launch_bounds__(256) void gather_x(
    const int* __restrict__ obs, const float* __restrict__ emb,
    float* __restrict__ x)
{
  const int idx = blockIdx.x * 256 + threadIdx.x;
  const int bt = idx >> 8, c = idx & 255;
  *(float4*)(x + (size_t)bt * 1024 + c * 4) =
      *(const float4*)(emb + (size_t)obs[bt] * 1024 + c * 4);
}

// ---------------------------------------------------------------- layernorm
__global__ __launch_bounds__(256) void ln_bf16(
    const float* __restrict__ x, const float* __restrict__ g,
    const float* __restrict__ bb, u16* __restrict__ out)
{
  const int row = blockIdx.x, tid = threadIdx.x;
  const float4 v = *(const float4*)(x + (size_t)row * 1024 + tid * 4);
  float s = v.x + v.y + v.z + v.w;
  float q = v.x * v.x + v.y * v.y + v.z * v.z + v.w * v.w;
  #pragma unroll
  for (int off = 32; off; off >>= 1) { s += __shfl_xor(s, off); q += __shfl_xor(q, off); }
  __shared__ float red[8];
  const int wid = tid >> 6, lane = tid & 63;
  if (lane == 0) { red[wid] = s; red[4 + wid] = q; }
  __syncthreads();
  s = red[0] + red[1] + red[2] + red[3];
  q = red[4] + red[5] + red[6] + red[7];
  const float mean = s * (1.f / 1024.f);
  const float var = q * (1.f / 1024.f) - mean * mean;
  const float rstd = rsqrtf(var + 1e-5f);
  float a0 = (v.x - mean) * rstd * g[tid * 4 + 0] + bb[tid * 4 + 0];
  float a1 = (v.y - mean) * rstd * g[tid * 4 + 1] + bb[tid * 4 + 1];
  float a2 = (v.z - mean) * rstd * g[tid * 4 + 2] + bb[tid * 4 + 2];
  float a3 = (v.w - mean) * rstd * g[tid * 4 + 3] + bb[tid * 4 + 3];
  uint2 pk;
  pk.x = (u32)f2bf(a0) | ((u32)f2bf(a1) << 16);
  pk.y = (u32)f2bf(a2) | ((u32)f2bf(a3) << 16);
  *(uint2*)(out + (size_t)row * 1024 + tid * 4) = pk;
}

// ---------------------------------------------------------------- GEMM
// C(2048,N) = A(2048,K)bf16 @ Bt(N,K)bf16^T + epilogue. 1-D swizzled grid:
// grid = 16*(N/128) blocks; blocks with the same N-strip land on one XCD
// (assumes round-robin linear-block -> XCD; perf heuristic only).
// MODE 0: +bias -> bf16        MODE 1: +bias+residual -> fp32 (in-place x)
// MODE 2: +bias, gelu -> bf16  MODE 3: +bias -> fp32
// MODE 5: fused QKV: N=3072; Q,K rotated via cs, V stored transposed [b,h,d,t]
template<int MODE>
__global__ __launch_bounds__(256) void gemm_bt(
    const u16* __restrict__ A, const u16* __restrict__ Bt,
    const float* __restrict__ bias, const float* res, void* outp,
    const float2* __restrict__ cs, int N, int K, int ypx)
{
  __shared__ u16 As[128 * 32];
  __shared__ u16 Bs[128 * 32];
  const int id = blockIdx.x;
  const int loc = id >> 3;
  const int bx = loc & 15;                       // M-tile (M=2048 fixed)
  const int by = (id & 7) * ypx + (loc >> 4);    // N-tile
  const int tid = threadIdx.x;
  const int lane = tid & 63, wid = tid >> 6;
  const int wm = wid & 1, wn = wid >> 1;
  const int quad = lane >> 4, lq = lane & 15;
  const int m0 = bx * 128, n0 = by * 128;

  f32x4 acc[4][4] = {};
  const int nkb = K >> 5;
  for (int kb = 0; kb < nkb; ++kb) {
    __syncthreads();
    const int kof = kb * 32;
    #pragma unroll
    for (int rep = 0; rep < 2; ++rep) {
      int c = rep * 256 + tid;
      int row = c >> 2, kc = (c & 3) * 8;
      gll16(A + (size_t)(m0 + row) * K + kof + kc, As + c * 8);
      gll16(Bt + (size_t)(n0 + row) * K + kof + kc, Bs + c * 8);
    }
    __syncthreads();
    bf16x8 a[4], b[4];
    #pragma unroll
    for (int i = 0; i < 4; ++i)
      a[i] = *(const bf16x8*)(As + (wm * 64 + i * 16 + lq) * 32 + quad * 8);
    #pragma unroll
    for (int j = 0; j < 4; ++j)
      b[j] = *(const bf16x8*)(Bs + (wn * 64 + j * 16 + lq) * 32 + quad * 8);
    #pragma unroll
    for (int i = 0; i < 4; ++i)
      #pragma unroll
      for (int j = 0; j < 4; ++j)
        acc[i][j] = __builtin_amdgcn_mfma_f32_16x16x32_bf16(a[i], b[j], acc[i][j], 0, 0, 0);
  }

  #pragma unroll
  for (int i = 0; i < 4; ++i) {
    const int gm0 = m0 + wm * 64 + i * 16 + quad * 4;
    #pragma unroll
    for (int j = 0; j < 4; ++j) {
      const int gn = n0 + wn * 64 + j * 16 + lq;
      const float bv = bias[gn];
      f32x4 v = acc[i][j];
      if constexpr (MODE == 0) {
        u16* O = (u16*)outp;
        #pragma unroll
        for (int r = 0; r < 4; ++r) O[(size_t)(gm0 + r) * N + gn] = f2bf(v[r] + bv);
      } else if constexpr (MODE == 1) {
        float* O = (float*)outp;
        #pragma unroll
        for (int r = 0; r < 4; ++r) {
          size_t idx = (size_t)(gm0 + r) * N + gn;
          O[idx] = res[idx] + v[r] + bv;
        }
      } else if constexpr (MODE == 2) {
        u16* O = (u16*)outp;
        #pragma unroll
        for (int r = 0; r < 4; ++r) {
          float t = v[r] + bv;
          O[(size_t)(gm0 + r) * N + gn] =
              f2bf(0.5f * t * (1.f + erff(t * 0.70710678118654752f)));
        }
      } else if constexpr (MODE == 3) {
        float* O = (float*)outp;
        #pragma unroll
        for (int r = 0; r < 4; ++r) O[(size_t)(gm0 + r) * N + gn] = v[r] + bv;
      } else {  // MODE 5: fused QKV
        u16* Qb = (u16*)outp;
        u16* Kb = Qb + (size_t)2048 * 1024;
        u16* Vtb = Kb + (size_t)2048 * 1024;
        const int region = gn >> 10;            // wave-uniform per (wn,j)
        if (region < 2) {
          u16* O = region ? Kb : Qb;
          const int dcol = gn & 1023;
          const int rb = (gn & 63) >> 1;
          const bool odd = (gn & 1) != 0;
          #pragma unroll
          for (int r = 0; r < 4; ++r) {
            float val = v[r] + bv;
            float part = __shfl_xor(val, 1);
            float2 c = cs[(size_t)(gm0 + r) * 32 + rb];
            float rot = odd ? (c.y * part + c.x * val)
                            : (c.x * val - c.y * part);
            O[(size_t)(gm0 + r) * 1024 + dcol] = f2bf(rot);
          }
        } else {
          const int gn2 = gn - 2048;
          const int b = gm0 >> 10, t = gm0 & 1023;
          u32 lo = (u32)f2bf(v[0] + bv) | ((u32)f2bf(v[1] + bv) << 16);
          u32 hi = (u32)f2bf(v[2] + bv) | ((u32)f2bf(v[3] + bv) << 16);
          uint2 pk; pk.x = lo; pk.y = hi;
          size_t idx = ((size_t)(b * 16 + (gn2 >> 6)) * 64 + (gn2 & 63)) * 1024 + t;
          *(uint2*)(Vtb + idx) = pk;
        }
      }
    }
  }
}

// ---------------------------------------------------------------- attention
// flash-style causal attention, 64x64 tiles, one block per (qt, b*H+h)
__global__ __launch_bounds__(256) void attn_kernel(
    const u16* __restrict__ Q, const u16* __restrict__ K,
    const u16* __restrict__ Vt, u16* __restrict__ O)
{
  __shared__ u16 Qs[64 * 80];
  __shared__ u16 Ks[64 * 80];
  __shared__ u16 Vs[64 * 80];
  __shared__ u16 Ps[64 * 80];

  const int tid = threadIdx.x;
  const int lane = tid & 63, wq = tid >> 6;
  const int quad = lane >> 4, lq = lane & 15;
  const int qt = blockIdx.x;
  const int bh = blockIdx.y;
  const int b = bh >> 4, h = bh & 15;

  const size_t qbase = (size_t)b * 1024 * 1024 + (size_t)qt * 64 * 1024 + h * 64;
  #pragma unroll
  for (int rep = 0; rep < 3; ++rep) {
    int c = rep * 256 + tid;
    if (c < 640) {
      int row = c / 10, rr = c % 10; if (rr >= 8) rr = 0;
      gll16(Q + qbase + (size_t)row * 1024 + rr * 8, Qs + c * 8);
    }
  }

  f32x4 o_acc[4] = {};
  float m_run[4], l_run[4];
  #pragma unroll
  for (int r = 0; r < 4; ++r) { m_run[r] = -1e30f; l_run[r] = 0.f; }

  for (int kt = 0; kt <= qt; ++kt) {
    __syncthreads();
    const size_t kbase = (size_t)b * 1024 * 1024 + (size_t)kt * 64 * 1024 + h * 64;
    const size_t vbase = (size_t)bh * 64 * 1024 + kt * 64;
    #pragma unroll
    for (int rep = 0; rep < 3; ++rep) {
      int c = rep * 256 + tid;
      if (c < 640) {
        int row = c / 10, rr = c % 10; if (rr >= 8) rr = 0;
        gll16(K + kbase + (size_t)row * 1024 + rr * 8, Ks + c * 8);
        gll16(Vt + vbase + (size_t)row * 1024 + rr * 8, Vs + c * 8);
      }
    }
    __syncthreads();

    f32x4 s[4] = {};
    #pragma unroll
    for (int ks = 0; ks < 2; ++ks) {
      bf16x8 aq = *(const bf16x8*)(Qs + (wq * 16 + lq) * 80 + ks * 32 + quad * 8);
      #pragma unroll
      for (int j = 0; j < 4; ++j) {
        bf16x8 bk = *(const bf16x8*)(Ks + (j * 16 + lq) * 80 + ks * 32 + quad * 8);
        s[j] = __builtin_amdgcn_mfma_f32_16x16x32_bf16(aq, bk, s[j], 0, 0, 0);
      }
    }

    float mt[4] = {-1e30f, -1e30f, -1e30f, -1e30f};
    const int qr0 = qt * 64 + wq * 16 + quad * 4;
    const bool diag = (kt == qt);
    #pragma unroll
    for (int j = 0; j < 4; ++j) {
      const int kp = kt * 64 + j * 16 + lq;
      #pragma unroll
      for (int r = 0; r < 4; ++r) {
        float v = s[j][r] * 0.125f;
        if (diag && kp > qr0 + r) v = -1e30f;
        s[j][r] = v;
        mt[r] = fmaxf(mt[r], v);
      }
    }
    #pragma unroll
    for (int r = 0; r < 4; ++r)
      #pragma unroll
      for (int off = 1; off < 16; off <<= 1)
        mt[r] = fmaxf(mt[r], __shfl_xor(mt[r], off));

    float alpha[4], rs[4];
    #pragma unroll
    for (int r = 0; r < 4; ++r) {
      float mn = fmaxf(m_run[r], mt[r]);
      alpha[r] = __expf(m_run[r] - mn);
      m_run[r] = mn;
      rs[r] = 0.f;
    }
    #pragma unroll
    for (int j = 0; j < 4; ++j)
      #pragma unroll
      for (int r = 0; r < 4; ++r) {
        float p = __expf(s[j][r] - m_run[r]);
        s[j][r] = p;
        rs[r] += p;
      }
    #pragma unroll
    for (int r = 0; r < 4; ++r) {
      #pragma unroll
      for (int off = 1; off < 16; off <<= 1)
        rs[r] += __shfl_xor(rs[r], off);
      l_run[r] = l_run[r] * alpha[r] + rs[r];
      o_acc[0][r] *= alpha[r]; o_acc[1][r] *= alpha[r];
      o_acc[2][r] *= alpha[r]; o_acc[3][r] *= alpha[r];
    }

    #pragma unroll
    for (int j = 0; j < 4; ++j)
      #pragma unroll
      for (int r = 0; r < 4; ++r)
        Ps[(wq * 16 + quad * 4 + r) * 80 + j * 16 + lq] = f2bf(s[j][r]);
    asm volatile("s_waitcnt lgkmcnt(0)" ::: "memory");

    #pragma unroll
    for (int ks = 0; ks < 2; ++ks) {
      bf16x8 ap = *(const bf16x8*)(Ps + (wq * 16 + lq) * 80 + ks * 32 + quad * 8);
      #pragma unroll
      for (int jd = 0; jd < 4; ++jd) {
        bf16x8 bv = *(const bf16x8*)(Vs + (jd * 16 + lq) * 80 + ks * 32 + quad * 8);
        o_acc[jd] = __builtin_amdgcn_mfma_f32_16x16x32_bf16(ap, bv, o_acc[jd], 0, 0, 0);
      }
    }
  }

  #pragma unroll
  for (int r = 0; r < 4; ++r) {
    const int t = qt * 64 + wq * 16 + quad * 4 + r;
    const float inv = 1.f / l_run[r];
    const size_t base = ((size_t)(b * 1024 + t) * 16 + h) * 64;
    #pragma unroll
    for (int jd = 0; jd < 4; ++jd)
      O[base + jd * 16 + lq] = f2bf(o_acc[jd][r] * inv);
  }
}

// ---------------------------------------------------------------- launch
extern "C" void kernel_launch(void* const* d_in, const int* in_sizes, int n_in,
                              void* d_out, int out_size, void* d_ws, size_t ws_size,
                              hipStream_t stream) {
  const int*   actions      = (const int*)d_in[0];
  const int*   observations = (const int*)d_in[1];
  const float* action_emb   = (const float*)d_in[2];
  const float* obs_emb      = (const float*)d_in[3];
  const float* lie_w        = (const float*)d_in[4];
  const float* lie_b        = (const float*)d_in[5];
  const float* Wq = (const float*)d_in[6];  const float* bq = (const float*)d_in[7];
  const float* Wk = (const float*)d_in[8];  const float* bk = (const float*)d_in[9];
  const float* Wv = (const float*)d_in[10]; const float* bvp = (const float*)d_in[11];
  const float* Wo = (const float*)d_in[12]; const float* bo = (const float*)d_in[13];
  const float* ln1_g = (const float*)d_in[14]; const float* ln1_b = (const float*)d_in[15];
  const float* ln2_g = (const float*)d_in[16]; const float* ln2_b = (const float*)d_in[17];
  const float* w1 = (const float*)d_in[18]; const float* b1 = (const float*)d_in[19];
  const float* w2 = (const float*)d_in[20]; const float* b2 = (const float*)d_in[21];
  const float* out_g = (const float*)d_in[22]; const float* out_bln = (const float*)d_in[23];
  const float* out_w = (const float*)d_in[24]; const float* out_b = (const float*)d_in[25];
  float* out = (float*)d_out;

  char* basep = (char*)d_ws;
  size_t off = 0;
  auto take = [&](size_t bytes) -> char* {
    char* p = basep + off;
    off += (bytes + 255) & ~(size_t)255;
    return p;
  };
  u16* qkvT = (u16*)take((size_t)2 * 3072 * 1024 * 2);   // [L][3072][1024]
  u16* woT  = (u16*)take((size_t)2 * 1024 * 1024 * 2);
  u16* w1T  = (u16*)take((size_t)2 * 4096 * 1024 * 2);
  u16* w2T  = (u16*)take((size_t)2 * 4096 * 1024 * 2);
  u16* owT  = (u16*)take((size_t)16384 * 1024 * 2);
  float* biasf = (float*)take((size_t)2 * 3072 * 4);
  float*  xbuf  = (float*)take((size_t)2048 * 1024 * 4);
  u16*    hbuf  = (u16*)take((size_t)2048 * 1024 * 2);
  u16*    qkvb  = (u16*)take((size_t)3 * 2048 * 1024 * 2);  // Q | K | V^T
  u16*    qbuf  = qkvb;
  u16*    kbuf  = qkvb + (size_t)2048 * 1024;
  u16*    vtg   = qkvb + (size_t)2 * 2048 * 1024;
  u16*    obuf  = (u16*)take((size_t)2048 * 1024 * 2);
  u16*    ubuf  = (u16*)take((size_t)2048 * 4096 * 2);
  float*  dbuf  = (float*)take((size_t)2048 * 32 * 4);
  float2* csbuf = (float2*)take((size_t)2048 * 32 * 8);

  for (int l = 0; l < 2; ++l) {
    size_t mo = (size_t)l * 1024 * 1024;
    size_t qo = (size_t)l * 3072 * 1024;
    size_t fo = (size_t)l * 4096 * 1024;
    transpose_f2b<<<dim3(16, 16), 256, 0, stream>>>(Wq + mo, qkvT + qo, 1024, 1024);
    transpose_f2b<<<dim3(16, 16), 256, 0, stream>>>(Wk + mo, qkvT + qo + (size_t)1024 * 1024, 1024, 1024);
    transpose_f2b<<<dim3(16, 16), 256, 0, stream>>>(Wv + mo, qkvT + qo + (size_t)2048 * 1024, 1024, 1024);
    transpose_f2b<<<dim3(16, 16), 256, 0, stream>>>(Wo + mo, woT + mo, 1024, 1024);
    transpose_f2b<<<dim3(64, 16), 256, 0, stream>>>(w1 + fo, w1T + fo, 1024, 4096);
    transpose_f2b<<<dim3(16, 64), 256, 0, stream>>>(w2 + fo, w2T + fo, 4096, 1024);
  }
  transpose_f2b<<<dim3(256, 16), 256, 0, stream>>>(out_w, owT, 1024, 16384);
  fuse_bias<<<24, 256, 0, stream>>>(bq, bk, bvp, biasf);

  delta_kernel<<<2048, 256, 0, stream>>>(actions, action_emb, lie_w, lie_b, dbuf);
  scan_theta<<<64, 256, 0, stream>>>(dbuf, csbuf);
  gather_x<<<2048, 256, 0, stream>>>(observations, obs_emb, xbuf);

  for (int l = 0; l < 2; ++l) {
    size_t mo = (size_t)l * 1024 * 1024;
    size_t qo = (size_t)l * 3072 * 1024;
    size_t fo = (size_t)l * 4096 * 1024;
    ln_bf16<<<2048, 256, 0, stream>>>(xbuf, ln1_g + l * 1024, ln1_b + l * 1024, hbuf);
    gemm_bt<5><<<16 * 24, 256, 0, stream>>>(hbuf, qkvT + qo, biasf + l * 3072, nullptr,
                                            qkvb, csbuf, 3072, 1024, 3);
    attn_kernel<<<dim3(16, 32), 256, 0, stream>>>(qbuf, kbuf, vtg, obuf);
    gemm_bt<1><<<16 * 8, 256, 0, stream>>>(obuf, woT + mo, bo + l * 1024, xbuf,
                                           xbuf, nullptr, 1024, 1024, 1);
    ln_bf16<<<2048, 256, 0, stream>>>(xbuf, ln2_g + l * 1024, ln2_b + l * 1024, hbuf);
    gemm_bt<2><<<16 * 32, 256, 0, stream>>>(hbuf, w1T + fo, b1 + l * 4096, nullptr,
                                            ubuf, nullptr, 4096, 1024, 4);
    gemm_bt<1><<<16 * 8, 256, 0, stream>>>(ubuf, w2T + fo, b2 + l * 1024, xbuf,
                                           xbuf, nullptr, 1024, 4096, 1);
  }
  ln_bf16<<<2048, 256, 0, stream>>>(xbuf, out_g, out_bln, hbuf);
  gemm_bt<3><<<16 * 128, 256, 0, stream>>>(hbuf, owT, out_b, nullptr,
                                           out, nullptr, 16384, 1024, 16);
}

// Round 3
// 912.920 us; speedup vs baseline: 1.2711x; 1.2134x over previous
//
#include <hip/hip_runtime.h>
#include <cstdint>
#include <cstddef>

// MapFormerWM: 2-layer transformer with SO(2)-block "generalized RoPE".
// Prefix product of commuting 2x2 rotations == rotation by cumsum of angles.
// Round 3: revert XCD swizzle (measured regression), split-K for N=1024 GEMMs
// with reduction fused into following LayerNorm, batched weight transposes.

using u16 = unsigned short;
using u32 = unsigned int;

typedef __bf16 bf16x8 __attribute__((ext_vector_type(8)));
typedef float  f32x4  __attribute__((ext_vector_type(4)));

__device__ __forceinline__ u16 f2bf(float f) {
  union { float f; u32 u; } v; v.f = f;
  u32 r = v.u + 0x7fffu + ((v.u >> 16) & 1u);   // RNE
  return (u16)(r >> 16);
}

// async global->LDS, 16B per lane; LDS dest must be wave-uniform base + lane*16
__device__ __forceinline__ void gll16(const void* g, void* l) {
  __builtin_amdgcn_global_load_lds((__attribute__((address_space(1))) void*)(g),
                                   (__attribute__((address_space(3))) void*)(l),
                                   16, 0, 0);
}

// ---------------------------------------------------------------- transposes
// fp32 (K,N) row-major -> bf16 (N,K) row-major, 64x64 tiles, z = batch index
__global__ __launch_bounds__(256) void transpose_f2b(
    const float* __restrict__ in0, u16* __restrict__ out0, int K, int N)
{
  const float* in = in0 + (size_t)blockIdx.z * K * N;
  u16* out = out0 + (size_t)blockIdx.z * K * N;
  __shared__ float tile[64][65];
  const int n0 = blockIdx.x * 64, k0 = blockIdx.y * 64;
  const int tid = threadIdx.x;
  const int rr = tid >> 4, cc = (tid & 15) * 4;
  #pragma unroll
  for (int p = 0; p < 4; ++p) {
    int kk = rr + p * 16;
    float4 v = *(const float4*)(in + (size_t)(k0 + kk) * N + n0 + cc);
    tile[kk][cc] = v.x; tile[kk][cc + 1] = v.y;
    tile[kk][cc + 2] = v.z; tile[kk][cc + 3] = v.w;
  }
  __syncthreads();
  #pragma unroll
  for (int p = 0; p < 4; ++p) {
    int nn = rr + p * 16;
    uint2 pk;
    pk.x = (u32)f2bf(tile[cc + 0][nn]) | ((u32)f2bf(tile[cc + 1][nn]) << 16);
    pk.y = (u32)f2bf(tile[cc + 2][nn]) | ((u32)f2bf(tile[cc + 3][nn]) << 16);
    *(uint2*)(out + (size_t)(n0 + nn) * K + k0 + cc) = pk;
  }
}

struct TP8 { const float* s[8]; u16* d[8]; };
// 8 independent 1024x1024 transposes in one launch, grid (16,16,8)
__global__ __launch_bounds__(256) void transpose8(TP8 p)
{
  const float* in = p.s[blockIdx.z];
  u16* out = p.d[blockIdx.z];
  __shared__ float tile[64][65];
  const int n0 = blockIdx.x * 64, k0 = blockIdx.y * 64;
  const int tid = threadIdx.x;
  const int rr = tid >> 4, cc = (tid & 15) * 4;
  #pragma unroll
  for (int p2 = 0; p2 < 4; ++p2) {
    int kk = rr + p2 * 16;
    float4 v = *(const float4*)(in + (size_t)(k0 + kk) * 1024 + n0 + cc);
    tile[kk][cc] = v.x; tile[kk][cc + 1] = v.y;
    tile[kk][cc + 2] = v.z; tile[kk][cc + 3] = v.w;
  }
  __syncthreads();
  #pragma unroll
  for (int p2 = 0; p2 < 4; ++p2) {
    int nn = rr + p2 * 16;
    uint2 pk;
    pk.x = (u32)f2bf(tile[cc + 0][nn]) | ((u32)f2bf(tile[cc + 1][nn]) << 16);
    pk.y = (u32)f2bf(tile[cc + 2][nn]) | ((u32)f2bf(tile[cc + 3][nn]) << 16);
    *(uint2*)(out + (size_t)(n0 + nn) * 1024 + k0 + cc) = pk;
  }
}

// fused qkv bias: out[l*3072 + r] from bq/bk/bv (each [L][1024])
__global__ __launch_bounds__(256) void fuse_bias(
    const float* __restrict__ bq, const float* __restrict__ bk,
    const float* __restrict__ bv, float* __restrict__ out)
{
  int idx = blockIdx.x * 256 + threadIdx.x;   // 6144
  int l = idx / 3072, r = idx % 3072;
  const float* src = (r < 1024) ? bq : ((r < 2048) ? bk : bv);
  out[idx] = src[l * 1024 + (r & 1023)];
}

// ---------------------------------------------------------------- delta
__global__ __launch_bounds__(256) void delta_kernel(
    const int* __restrict__ actions, const float* __restrict__ aemb,
    const float* __restrict__ lie_w, const float* __restrict__ lie_b,
    float* __restrict__ delta)
{
  const int bt = blockIdx.x;                 // 0..2047
  const int a = actions[bt];
  const float* e = aemb + (size_t)a * 1024;
  const int r = threadIdx.x >> 3, part = threadIdx.x & 7;
  float s = 0.f;
  const int j0 = part * 128;
  for (int j = j0; j < j0 + 128; ++j)
    s += e[j] * lie_w[(size_t)j * 32 + r];
  s += __shfl_xor(s, 1); s += __shfl_xor(s, 2); s += __shfl_xor(s, 4);
  if (part == 0) delta[(size_t)bt * 32 + r] = s + lie_b[r];
}

// ---------------------------------------------------------------- scan
__global__ __launch_bounds__(256) void scan_theta(
    const float* __restrict__ delta, float2* __restrict__ cs)
{
  const int b = blockIdx.x >> 5, r = blockIdx.x & 31;
  const int tid = threadIdx.x;
  float d0[4];
  #pragma unroll
  for (int i = 0; i < 4; ++i)
    d0[i] = delta[((size_t)b * 1024 + tid * 4 + i) * 32 + r];
  d0[1] += d0[0]; d0[2] += d0[1]; d0[3] += d0[2];
  __shared__ float sc[256];
  sc[tid] = d0[3];
  __syncthreads();
  for (int off = 1; off < 256; off <<= 1) {
    float v = (tid >= off) ? sc[tid - off] : 0.f;
    __syncthreads();
    sc[tid] += v;
    __syncthreads();
  }
  float ex = sc[tid] - d0[3];
  #pragma unroll
  for (int i = 0; i < 4; ++i) {
    float th = ex + d0[i];
    float2 v; v.x = cosf(th); v.y = sinf(th);
    cs[((size_t)b * 1024 + tid * 4 + i) * 32 + r] = v;
  }
}

// ---------------------------------------------------------------- gather x
__global__ __launch_bounds__(256) void gather_x(
    const int* __restrict__ obs, const float* __restrict__ emb,
    float* __restrict__ x)
{
  const int idx = blockIdx.x * 256 + threadIdx.x;
  const int bt = idx >> 8, c = idx & 255;
  *(float4*)(x + (size_t)bt * 1024 + c * 4) =
      *(const float4*)(emb + (size_t)obs[bt] * 1024 + c * 4);
}

// ---------------------------------------------------------------- layernorm
// plain: x fp32 row -> bf16 normalized
__global__ __launch_bounds__(256) void ln_bf16(
    const float* __restrict__ x, const float* __restrict__ g,
    const float* __restrict__ bb, u16* __restrict__ out)
{
  const int row = blockIdx.x, tid = threadIdx.x;
  const float4 v = *(const float4*)(x + (size_t)row * 1024 + tid * 4);
  float s = v.x + v.y + v.z + v.w;
  float q = v.x * v.x + v.y * v.y + v.z * v.z + v.w * v.w;
  #pragma unroll
  for (int off = 32; off; off >>= 1) { s += __shfl_xor(s, off); q += __shfl_xor(q, off); }
  __shared__ float red[8];
  const int wid = tid >> 6, lane = tid & 63;
  if (lane == 0) { red[wid] = s; red[4 + wid] = q; }
  __syncthreads();
  s = red[0] + red[1] + red[2] + red[3];
  q = red[4] + red[5] + red[6] + red[7];
  const float mean = s * (1.f / 1024.f);
  const float var = q * (1.f / 1024.f) - mean * mean;
  const float rstd = rsqrtf(var + 1e-5f);
  float a0 = (v.x - mean) * rstd * g[tid * 4 + 0] + bb[tid * 4 + 0];
  float a1 = (v.y - mean) * rstd * g[tid * 4 + 1] + bb[tid * 4 + 1];
  float a2 = (v.z - mean) * rstd * g[tid * 4 + 2] + bb[tid * 4 + 2];
  float a3 = (v.w - mean) * rstd * g[tid * 4 + 3] + bb[tid * 4 + 3];
  uint2 pk;
  pk.x = (u32)f2bf(a0) | ((u32)f2bf(a1) << 16);
  pk.y = (u32)f2bf(a2) | ((u32)f2bf(a3) << 16);
  *(uint2*)(out + (size_t)row * 1024 + tid * 4) = pk;
}

// fused reduce + residual + bias + layernorm:
//   xnew = x + bias + sum_{s<sk} part[s]; x <- xnew (fp32); out <- LN(xnew) bf16
__global__ __launch_bounds__(256) void ln_red(
    float* __restrict__ x, const float* __restrict__ part, int sk,
    const float* __restrict__ bias, const float* __restrict__ g,
    const float* __restrict__ bb, u16* __restrict__ out)
{
  const int row = blockIdx.x, tid = threadIdx.x;
  const size_t base = (size_t)row * 1024 + tid * 4;
  float4 v = *(const float4*)(x + base);
  const float4 bia = *(const float4*)(bias + tid * 4);
  v.x += bia.x; v.y += bia.y; v.z += bia.z; v.w += bia.w;
  for (int sp = 0; sp < sk; ++sp) {
    float4 pv = *(const float4*)(part + (size_t)sp * 2048 * 1024 + base);
    v.x += pv.x; v.y += pv.y; v.z += pv.z; v.w += pv.w;
  }
  *(float4*)(x + base) = v;
  float s = v.x + v.y + v.z + v.w;
  float q = v.x * v.x + v.y * v.y + v.z * v.z + v.w * v.w;
  #pragma unroll
  for (int off = 32; off; off >>= 1) { s += __shfl_xor(s, off); q += __shfl_xor(q, off); }
  __shared__ float red[8];
  const int wid = tid >> 6, lane = tid & 63;
  if (lane == 0) { red[wid] = s; red[4 + wid] = q; }
  __syncthreads();
  s = red[0] + red[1] + red[2] + red[3];
  q = red[4] + red[5] + red[6] + red[7];
  const float mean = s * (1.f / 1024.f);
  const float var = q * (1.f / 1024.f) - mean * mean;
  const float rstd = rsqrtf(var + 1e-5f);
  float a0 = (v.x - mean) * rstd * g[tid * 4 + 0] + bb[tid * 4 + 0];
  float a1 = (v.y - mean) * rstd * g[tid * 4 + 1] + bb[tid * 4 + 1];
  float a2 = (v.z - mean) * rstd * g[tid * 4 + 2] + bb[tid * 4 + 2];
  float a3 = (v.w - mean) * rstd * g[tid * 4 + 3] + bb[tid * 4 + 3];
  uint2 pk;
  pk.x = (u32)f2bf(a0) | ((u32)f2bf(a1) << 16);
  pk.y = (u32)f2bf(a2) | ((u32)f2bf(a3) << 16);
  *(uint2*)(out + base) = pk;
}

// ---------------------------------------------------------------- GEMM
// C(2048,N) = A(2048,Kfull)bf16 @ Bt(N,Kfull)^T, K-chunk = Kc per z-slice.
// grid (16, N/128, SK).  A/Bt rows have stride ldk; k-offset = z*Kc.
// MODE 0: +bias -> bf16        MODE 2: +bias, gelu -> bf16
// MODE 3: +bias -> fp32        MODE 5: fused QKV (rotate Q,K; V transposed)
// MODE 6: raw fp32 partial -> outp + z*2048*N (no bias)
template<int MODE>
__global__ __launch_bounds__(256) void gemm_bt(
    const u16* __restrict__ A, const u16* __restrict__ Bt,
    const float* __restrict__ bias, void* outp,
    const float2* __restrict__ cs, int N, int Kc, int ldk)
{
  __shared__ u16 As[128 * 32];
  __shared__ u16 Bs[128 * 32];
  const int tid = threadIdx.x;
  const int lane = tid & 63, wid = tid >> 6;
  const int wm = wid & 1, wn = wid >> 1;
  const int quad = lane >> 4, lq = lane & 15;
  const int m0 = blockIdx.x * 128, n0 = blockIdx.y * 128;
  const int koff = blockIdx.z * Kc;

  f32x4 acc[4][4] = {};
  const int nkb = Kc >> 5;
  for (int kb = 0; kb < nkb; ++kb) {
    __syncthreads();
    const int kof = koff + kb * 32;
    #pragma unroll
    for (int rep = 0; rep < 2; ++rep) {
      int c = rep * 256 + tid;
      int row = c >> 2, kc = (c & 3) * 8;
      gll16(A + (size_t)(m0 + row) * ldk + kof + kc, As + c * 8);
      gll16(Bt + (size_t)(n0 + row) * ldk + kof + kc, Bs + c * 8);
    }
    __syncthreads();
    bf16x8 a[4], b[4];
    #pragma unroll
    for (int i = 0; i < 4; ++i)
      a[i] = *(const bf16x8*)(As + (wm * 64 + i * 16 + lq) * 32 + quad * 8);
    #pragma unroll
    for (int j = 0; j < 4; ++j)
      b[j] = *(const bf16x8*)(Bs + (wn * 64 + j * 16 + lq) * 32 + quad * 8);
    #pragma unroll
    for (int i = 0; i < 4; ++i)
      #pragma unroll
      for (int j = 0; j < 4; ++j)
        acc[i][j] = __builtin_amdgcn_mfma_f32_16x16x32_bf16(a[i], b[j], acc[i][j], 0, 0, 0);
  }

  #pragma unroll
  for (int i = 0; i < 4; ++i) {
    const int gm0 = m0 + wm * 64 + i * 16 + quad * 4;
    #pragma unroll
    for (int j = 0; j < 4; ++j) {
      const int gn = n0 + wn * 64 + j * 16 + lq;
      f32x4 v = acc[i][j];
      if constexpr (MODE == 0) {
        const float bv = bias[gn];
        u16* O = (u16*)outp;
        #pragma unroll
        for (int r = 0; r < 4; ++r) O[(size_t)(gm0 + r) * N + gn] = f2bf(v[r] + bv);
      } else if constexpr (MODE == 2) {
        const float bv = bias[gn];
        u16* O = (u16*)outp;
        #pragma unroll
        for (int r = 0; r < 4; ++r) {
          float t = v[r] + bv;
          O[(size_t)(gm0 + r) * N + gn] =
              f2bf(0.5f * t * (1.f + erff(t * 0.70710678118654752f)));
        }
      } else if constexpr (MODE == 3) {
        const float bv = bias[gn];
        float* O = (float*)outp;
        #pragma unroll
        for (int r = 0; r < 4; ++r) O[(size_t)(gm0 + r) * N + gn] = v[r] + bv;
      } else if constexpr (MODE == 6) {
        float* O = (float*)outp + (size_t)blockIdx.z * 2048 * N;
        #pragma unroll
        for (int r = 0; r < 4; ++r) O[(size_t)(gm0 + r) * N + gn] = v[r];
      } else {  // MODE 5: fused QKV
        const float bv = bias[gn];
        u16* Qb = (u16*)outp;
        u16* Kb = Qb + (size_t)2048 * 1024;
        u16* Vtb = Kb + (size_t)2048 * 1024;
        const int region = gn >> 10;            // wave-uniform per (wn,j)
        if (region < 2) {
          u16* O = region ? Kb : Qb;
          const int dcol = gn & 1023;
          const int rb = (gn & 63) >> 1;
          const bool odd = (gn & 1) != 0;
          #pragma unroll
          for (int r = 0; r < 4; ++r) {
            float val = v[r] + bv;
            float part = __shfl_xor(val, 1);
            float2 c = cs[(size_t)(gm0 + r) * 32 + rb];
            float rot = odd ? (c.y * part + c.x * val)
                            : (c.x * val - c.y * part);
            O[(size_t)(gm0 + r) * 1024 + dcol] = f2bf(rot);
          }
        } else {
          const int gn2 = gn - 2048;
          const int b = gm0 >> 10, t = gm0 & 1023;
          uint2 pk;
          pk.x = (u32)f2bf(v[0] + bv) | ((u32)f2bf(v[1] + bv) << 16);
          pk.y = (u32)f2bf(v[2] + bv) | ((u32)f2bf(v[3] + bv) << 16);
          size_t idx = ((size_t)(b * 16 + (gn2 >> 6)) * 64 + (gn2 & 63)) * 1024 + t;
          *(uint2*)(Vtb + idx) = pk;
        }
      }
    }
  }
}

// ---------------------------------------------------------------- attention
// flash-style causal attention, 64x64 tiles, one block per (qt, b*H+h)
__global__ __launch_bounds__(256) void attn_kernel(
    const u16* __restrict__ Q, const u16* __restrict__ K,
    const u16* __restrict__ Vt, u16* __restrict__ O)
{
  __shared__ u16 Qs[64 * 80];
  __shared__ u16 Ks[64 * 80];
  __shared__ u16 Vs[64 * 80];
  __shared__ u16 Ps[64 * 80];

  const int tid = threadIdx.x;
  const int lane = tid & 63, wq = tid >> 6;
  const int quad = lane >> 4, lq = lane & 15;
  const int qt = blockIdx.x;
  const int bh = blockIdx.y;
  const int b = bh >> 4, h = bh & 15;

  const size_t qbase = (size_t)b * 1024 * 1024 + (size_t)qt * 64 * 1024 + h * 64;
  #pragma unroll
  for (int rep = 0; rep < 3; ++rep) {
    int c = rep * 256 + tid;
    if (c < 640) {
      int row = c / 10, rr = c % 10; if (rr >= 8) rr = 0;
      gll16(Q + qbase + (size_t)row * 1024 + rr * 8, Qs + c * 8);
    }
  }

  f32x4 o_acc[4] = {};
  float m_run[4], l_run[4];
  #pragma unroll
  for (int r = 0; r < 4; ++r) { m_run[r] = -1e30f; l_run[r] = 0.f; }

  for (int kt = 0; kt <= qt; ++kt) {
    __syncthreads();
    const size_t kbase = (size_t)b * 1024 * 1024 + (size_t)kt * 64 * 1024 + h * 64;
    const size_t vbase = (size_t)bh * 64 * 1024 + kt * 64;
    #pragma unroll
    for (int rep = 0; rep < 3; ++rep) {
      int c = rep * 256 + tid;
      if (c < 640) {
        int row = c / 10, rr = c % 10; if (rr >= 8) rr = 0;
        gll16(K + kbase + (size_t)row * 1024 + rr * 8, Ks + c * 8);
        gll16(Vt + vbase + (size_t)row * 1024 + rr * 8, Vs + c * 8);
      }
    }
    __syncthreads();

    f32x4 s[4] = {};
    #pragma unroll
    for (int ks = 0; ks < 2; ++ks) {
      bf16x8 aq = *(const bf16x8*)(Qs + (wq * 16 + lq) * 80 + ks * 32 + quad * 8);
      #pragma unroll
      for (int j = 0; j < 4; ++j) {
        bf16x8 bk = *(const bf16x8*)(Ks + (j * 16 + lq) * 80 + ks * 32 + quad * 8);
        s[j] = __builtin_amdgcn_mfma_f32_16x16x32_bf16(aq, bk, s[j], 0, 0, 0);
      }
    }

    float mt[4] = {-1e30f, -1e30f, -1e30f, -1e30f};
    const int qr0 = qt * 64 + wq * 16 + quad * 4;
    const bool diag = (kt == qt);
    #pragma unroll
    for (int j = 0; j < 4; ++j) {
      const int kp = kt * 64 + j * 16 + lq;
      #pragma unroll
      for (int r = 0; r < 4; ++r) {
        float v = s[j][r] * 0.125f;
        if (diag && kp > qr0 + r) v = -1e30f;
        s[j][r] = v;
        mt[r] = fmaxf(mt[r], v);
      }
    }
    #pragma unroll
    for (int r = 0; r < 4; ++r)
      #pragma unroll
      for (int off = 1; off < 16; off <<= 1)
        mt[r] = fmaxf(mt[r], __shfl_xor(mt[r], off));

    float alpha[4], rs[4];
    #pragma unroll
    for (int r = 0; r < 4; ++r) {
      float mn = fmaxf(m_run[r], mt[r]);
      alpha[r] = __expf(m_run[r] - mn);
      m_run[r] = mn;
      rs[r] = 0.f;
    }
    #pragma unroll
    for (int j = 0; j < 4; ++j)
      #pragma unroll
      for (int r = 0; r < 4; ++r) {
        float p = __expf(s[j][r] - m_run[r]);
        s[j][r] = p;
        rs[r] += p;
      }
    #pragma unroll
    for (int r = 0; r < 4; ++r) {
      #pragma unroll
      for (int off = 1; off < 16; off <<= 1)
        rs[r] += __shfl_xor(rs[r], off);
      l_run[r] = l_run[r] * alpha[r] + rs[r];
      o_acc[0][r] *= alpha[r]; o_acc[1][r] *= alpha[r];
      o_acc[2][r] *= alpha[r]; o_acc[3][r] *= alpha[r];
    }

    #pragma unroll
    for (int j = 0; j < 4; ++j)
      #pragma unroll
      for (int r = 0; r < 4; ++r)
        Ps[(wq * 16 + quad * 4 + r) * 80 + j * 16 + lq] = f2bf(s[j][r]);
    asm volatile("s_waitcnt lgkmcnt(0)" ::: "memory");

    #pragma unroll
    for (int ks = 0; ks < 2; ++ks) {
      bf16x8 ap = *(const bf16x8*)(Ps + (wq * 16 + lq) * 80 + ks * 32 + quad * 8);
      #pragma unroll
      for (int jd = 0; jd < 4; ++jd) {
        bf16x8 bv = *(const bf16x8*)(Vs + (jd * 16 + lq) * 80 + ks * 32 + quad * 8);
        o_acc[jd] = __builtin_amdgcn_mfma_f32_16x16x32_bf16(ap, bv, o_acc[jd], 0, 0, 0);
      }
    }
  }

  #pragma unroll
  for (int r = 0; r < 4; ++r) {
    const int t = qt * 64 + wq * 16 + quad * 4 + r;
    const float inv = 1.f / l_run[r];
    const size_t base = ((size_t)(b * 1024 + t) * 16 + h) * 64;
    #pragma unroll
    for (int jd = 0; jd < 4; ++jd)
      O[base + jd * 16 + lq] = f2bf(o_acc[jd][r] * inv);
  }
}

// ---------------------------------------------------------------- launch
extern "C" void kernel_launch(void* const* d_in, const int* in_sizes, int n_in,
                              void* d_out, int out_size, void* d_ws, size_t ws_size,
                              hipStream_t stream) {
  const int*   actions      = (const int*)d_in[0];
  const int*   observations = (const int*)d_in[1];
  const float* action_emb   = (const float*)d_in[2];
  const float* obs_emb      = (const float*)d_in[3];
  const float* lie_w        = (const float*)d_in[4];
  const float* lie_b        = (const float*)d_in[5];
  const float* Wq = (const float*)d_in[6];  const float* bq = (const float*)d_in[7];
  const float* Wk = (const float*)d_in[8];  const float* bk = (const float*)d_in[9];
  const float* Wv = (const float*)d_in[10]; const float* bvp = (const float*)d_in[11];
  const float* Wo = (const float*)d_in[12]; const float* bo = (const float*)d_in[13];
  const float* ln1_g = (const float*)d_in[14]; const float* ln1_b = (const float*)d_in[15];
  const float* ln2_g = (const float*)d_in[16]; const float* ln2_b = (const float*)d_in[17];
  const float* w1 = (const float*)d_in[18]; const float* b1 = (const float*)d_in[19];
  const float* w2 = (const float*)d_in[20]; const float* b2 = (const float*)d_in[21];
  const float* out_g = (const float*)d_in[22]; const float* out_bln = (const float*)d_in[23];
  const float* out_w = (const float*)d_in[24]; const float* out_b = (const float*)d_in[25];
  float* out = (float*)d_out;

  char* basep = (char*)d_ws;
  size_t off = 0;
  auto take = [&](size_t bytes) -> char* {
    char* p = basep + off;
    off += (bytes + 255) & ~(size_t)255;
    return p;
  };
  u16* qkvT = (u16*)take((size_t)2 * 3072 * 1024 * 2);   // [L][3072][1024]
  u16* woT  = (u16*)take((size_t)2 * 1024 * 1024 * 2);
  u16* w1T  = (u16*)take((size_t)2 * 4096 * 1024 * 2);
  u16* w2T  = (u16*)take((size_t)2 * 4096 * 1024 * 2);
  u16* owT  = (u16*)take((size_t)16384 * 1024 * 2);
  float* biasf = (float*)take((size_t)2 * 3072 * 4);
  float*  xbuf  = (float*)take((size_t)2048 * 1024 * 4);
  u16*    hbuf  = (u16*)take((size_t)2048 * 1024 * 2);
  u16*    qkvb  = (u16*)take((size_t)3 * 2048 * 1024 * 2);  // Q | K | V^T
  u16*    qbuf  = qkvb;
  u16*    kbuf  = qkvb + (size_t)2048 * 1024;
  u16*    vtg   = qkvb + (size_t)2 * 2048 * 1024;
  u16*    obuf  = (u16*)take((size_t)2048 * 1024 * 2);
  u16*    ubuf  = (u16*)take((size_t)2048 * 4096 * 2);
  float*  partW = (float*)ubuf;   // alias: disjoint lifetimes (wo->ln_red vs ffn1->ffn2)
  float*  partF = (float*)take((size_t)4 * 2048 * 1024 * 4);
  float*  dbuf  = (float*)take((size_t)2048 * 32 * 4);
  float2* csbuf = (float2*)take((size_t)2048 * 32 * 8);

  // ---- weight prep (4 launches) ----
  TP8 tp;
  for (int l = 0; l < 2; ++l) {
    size_t mo = (size_t)l * 1024 * 1024;
    size_t qo = (size_t)l * 3072 * 1024;
    tp.s[l * 4 + 0] = Wq + mo; tp.d[l * 4 + 0] = qkvT + qo;
    tp.s[l * 4 + 1] = Wk + mo; tp.d[l * 4 + 1] = qkvT + qo + (size_t)1024 * 1024;
    tp.s[l * 4 + 2] = Wv + mo; tp.d[l * 4 + 2] = qkvT + qo + (size_t)2048 * 1024;
    tp.s[l * 4 + 3] = Wo + mo; tp.d[l * 4 + 3] = woT + mo;
  }
  transpose8<<<dim3(16, 16, 8), 256, 0, stream>>>(tp);
  transpose_f2b<<<dim3(64, 16, 2), 256, 0, stream>>>(w1, w1T, 1024, 4096);
  transpose_f2b<<<dim3(16, 64, 2), 256, 0, stream>>>(w2, w2T, 4096, 1024);
  transpose_f2b<<<dim3(256, 16, 1), 256, 0, stream>>>(out_w, owT, 1024, 16384);
  fuse_bias<<<24, 256, 0, stream>>>(bq, bk, bvp, biasf);

  delta_kernel<<<2048, 256, 0, stream>>>(actions, action_emb, lie_w, lie_b, dbuf);
  scan_theta<<<64, 256, 0, stream>>>(dbuf, csbuf);
  gather_x<<<2048, 256, 0, stream>>>(observations, obs_emb, xbuf);

  ln_bf16<<<2048, 256, 0, stream>>>(xbuf, ln1_g, ln1_b, hbuf);
  for (int l = 0; l < 2; ++l) {
    size_t mo = (size_t)l * 1024 * 1024;
    size_t qo = (size_t)l * 3072 * 1024;
    size_t fo = (size_t)l * 4096 * 1024;
    gemm_bt<5><<<dim3(16, 24, 1), 256, 0, stream>>>(hbuf, qkvT + qo, biasf + l * 3072,
                                                    qkvb, csbuf, 3072, 1024, 1024);
    attn_kernel<<<dim3(16, 32), 256, 0, stream>>>(qbuf, kbuf, vtg, obuf);
    // Wo: split-K=2 partials, reduce fused into ln2
    gemm_bt<6><<<dim3(16, 8, 2), 256, 0, stream>>>(obuf, woT + mo, nullptr,
                                                   partW, nullptr, 1024, 512, 1024);
    ln_red<<<2048, 256, 0, stream>>>(xbuf, partW, 2, bo + l * 1024,
                                     ln2_g + l * 1024, ln2_b + l * 1024, hbuf);
    gemm_bt<2><<<dim3(16, 32, 1), 256, 0, stream>>>(hbuf, w1T + fo, b1 + l * 4096,
                                                    ubuf, nullptr, 4096, 1024, 1024);
    // FFN2: split-K=4 partials, reduce fused into next LN
    gemm_bt<6><<<dim3(16, 8, 4), 256, 0, stream>>>(ubuf, w2T + fo, nullptr,
                                                   partF, nullptr, 1024, 1024, 4096);
    const float* ng = (l == 0) ? (ln1_g + 1024) : out_g;
    const float* nb = (l == 0) ? (ln1_b + 1024) : out_bln;
    ln_red<<<2048, 256, 0, stream>>>(xbuf, partF, 4, b2 + l * 1024, ng, nb, hbuf);
  }
  gemm_bt<3><<<dim3(16, 128, 1), 256, 0, stream>>>(hbuf, owT, out_b,
                                                   out, nullptr, 16384, 1024, 1024);
}